// Round 10
// baseline (1246.756 us; speedup 1.0000x reference)
//
#include <hip/hip_runtime.h>

// Problem constants
constexpr int Bn  = 128;
constexpr int Tn  = 48000;
constexpr int NFn = 2999;   // fast frames
constexpr int NSn = 999;    // slow frames
constexpr int G3n = 192;    // 3*GH
constexpr int GHn = 64;

typedef float f2 __attribute__((ext_vector_type(2)));
typedef float f4 __attribute__((ext_vector_type(4)));

__device__ __forceinline__ float fsigmoid(float v) {
  return __fdividef(1.0f, 1.0f + __expf(-v));
}
__device__ __forceinline__ float ftanh_f(float v) {
  return 1.0f - __fdividef(2.0f, __expf(2.0f * v) + 1.0f);
}

// ---------------------------------------------------------------------------
// GRU body (round-0 proven, 485us). POLL=true adds per-32-step-chunk flag
// waits (r6-proven machinery: acquire agent-scope load + threadfence;
// producer side does threadfence + release fetch_add). Flag value 3 = all
// three 64-row gate tiles of that (b, chunk) are in GI.
// ---------------------------------------------------------------------------
template <bool POLL>
__device__ __forceinline__ void gru_body(const float* __restrict__ GI,
                                         const float* __restrict__ W_hh,
                                         const float* __restrict__ b_hh,
                                         float* __restrict__ hs,
                                         float* hbuf, int b, int j,
                                         unsigned int* flags) {
  f2 wr2[32], wz2[32], wn2[32];
  const f2* Wr = (const f2*)(W_hh + (size_t)j * 64);
  const f2* Wz = (const f2*)(W_hh + (size_t)(j + 64) * 64);
  const f2* Wn = (const f2*)(W_hh + (size_t)(j + 128) * 64);
#pragma unroll
  for (int q = 0; q < 32; ++q) { wr2[q] = Wr[q]; wz2[q] = Wz[q]; wn2[q] = Wn[q]; }
  // Opaque to the compiler => cannot re-load from memory inside the loop.
#pragma unroll
  for (int q = 0; q < 32; ++q) {
    asm volatile("" : "+v"(wr2[q]));
    asm volatile("" : "+v"(wz2[q]));
    asm volatile("" : "+v"(wn2[q]));
  }
  const float br = b_hh[j], bz = b_hh[j + 64], bn = b_hh[j + 128];

  unsigned int* fl = POLL ? (flags + b * 32) : nullptr;
  int cur_tc = 0;
  if (POLL) {
    if (j == 0) {
      while (__hip_atomic_load(&fl[0], __ATOMIC_ACQUIRE,
                               __HIP_MEMORY_SCOPE_AGENT) < 3u)
        __builtin_amdgcn_s_sleep(4);
    }
    __builtin_amdgcn_wave_barrier();
    __threadfence();
  }

  hbuf[j] = 0.0f;
  float hj = 0.0f;
  __builtin_amdgcn_wave_barrier();

  const float* gp = GI + (size_t)b * NSn * G3n;
  float* hsp = hs + (size_t)b * NSn * GHn;

  // distance-2 prefetch ring
  float pr0, pr1, pr2, pz0, pz1, pz2, pn0, pn1, pn2;
  pr0 = gp[0 * G3n + j];       pz0 = gp[0 * G3n + 64 + j];  pn0 = gp[0 * G3n + 128 + j];
  pr1 = gp[1 * G3n + j];       pz1 = gp[1 * G3n + 64 + j];  pn1 = gp[1 * G3n + 128 + j];

  for (int t = 0; t < NSn; ++t) {
    const int tn = min(t + 2, NSn - 1);
    if (POLL) {
      const int tc2 = tn >> 5;
      if (tc2 != cur_tc) {
        if (j == 0) {
          while (__hip_atomic_load(&fl[tc2], __ATOMIC_ACQUIRE,
                                   __HIP_MEMORY_SCOPE_AGENT) < 3u)
            __builtin_amdgcn_s_sleep(4);
        }
        __builtin_amdgcn_wave_barrier();
        __threadfence();
        cur_tc = tc2;
      }
    }
    const size_t off = (size_t)tn * G3n;
    pr2 = gp[off + j];
    pz2 = gp[off + 64 + j];
    pn2 = gp[off + 128 + j];

    const f2* h2 = (const f2*)hbuf;
    f2 ar0 = {0.f, 0.f}, ar1 = {0.f, 0.f}, ar2 = {0.f, 0.f}, ar3 = {0.f, 0.f};
    f2 az0 = {0.f, 0.f}, az1 = {0.f, 0.f}, az2 = {0.f, 0.f}, az3 = {0.f, 0.f};
    f2 an0 = {0.f, 0.f}, an1 = {0.f, 0.f}, an2 = {0.f, 0.f}, an3 = {0.f, 0.f};
#pragma unroll
    for (int q = 0; q < 8; ++q) {
      f2 h0 = h2[q * 4 + 0], h1 = h2[q * 4 + 1], h2v = h2[q * 4 + 2], h3 = h2[q * 4 + 3];
      ar0 += wr2[q * 4 + 0] * h0; ar1 += wr2[q * 4 + 1] * h1;
      ar2 += wr2[q * 4 + 2] * h2v; ar3 += wr2[q * 4 + 3] * h3;
      az0 += wz2[q * 4 + 0] * h0; az1 += wz2[q * 4 + 1] * h1;
      az2 += wz2[q * 4 + 2] * h2v; az3 += wz2[q * 4 + 3] * h3;
      an0 += wn2[q * 4 + 0] * h0; an1 += wn2[q * 4 + 1] * h1;
      an2 += wn2[q * 4 + 2] * h2v; an3 += wn2[q * 4 + 3] * h3;
    }
    f2 sr = (ar0 + ar1) + (ar2 + ar3);
    f2 sz = (az0 + az1) + (az2 + az3);
    f2 sn = (an0 + an1) + (an2 + an3);

    float r = fsigmoid(pr0 + br + sr.x + sr.y);
    float z = fsigmoid(pz0 + bz + sz.x + sz.y);
    float n = ftanh_f(fmaf(r, bn + sn.x + sn.y, pn0));
    float hn = fmaf(z, hj - n, n);          // (1-z)*n + z*h

    __builtin_amdgcn_wave_barrier();
    hbuf[j] = hn;
    __builtin_amdgcn_wave_barrier();
    hj = hn;
    hsp[(size_t)t * GHn + j] = hn;

    pr0 = pr1; pr1 = pr2;
    pz0 = pz1; pz1 = pz2;
    pn0 = pn1; pn1 = pn2;
  }
}

// ---------------------------------------------------------------------------
// FAT3 kernel, 64-thr blocks, 1 wave/SIMD:
//  [0,128):            gru (POLL per 32-step chunk), setprio(1).
//  [128, 128+12288):   gi producer tiles (b, tc, gate-64), tc-MAJOR order so
//                      chunk 0 for all b completes first. Tile uses the
//                      proven r0 decomposition cut to 64 threads: W gate-
//                      slice staged once in LDS [96][68], xs in LDS, b128
//                      reads, 8 independent acc chains, k ascending 0..95 =>
//                      bitwise-identical GI. GI -> global; threadfence +
//                      release fetch_add on flags[b*32+tc].
//  [12416, +3072):     U filler (r4-proven).
// Producers live on NON-gru CUs (gru CUs' spare slots host some transiently
// — unlike r9 there is NO barrier coupling and the traffic is brief).
// Deadlock-free in ANY dispatch order: gru only waits on flags; producers
// wait on nothing; 128 polling blocks << wave slots.
// ---------------------------------------------------------------------------
constexpr int UCHUNK = 125;
constexpr int NCH    = 24;              // 24*125 = 3000 >= 2999
constexpr int NPROD  = Bn * 32 * 3;     // 12288

__global__ __attribute__((amdgpu_flat_work_group_size(64, 64),
                          amdgpu_waves_per_eu(1, 1),
                          amdgpu_num_vgpr(256)))
void fat3_kernel(const float* __restrict__ x,
                 const float* __restrict__ W_ih,
                 const float* __restrict__ b_ih,
                 const float* __restrict__ W_hh,
                 const float* __restrict__ b_hh,
                 const float* __restrict__ W1,
                 const float* __restrict__ b1,
                 float* __restrict__ GI,
                 float* __restrict__ hs,
                 float* __restrict__ U,
                 unsigned int* __restrict__ flags) {
  __shared__ __align__(16) float smem[8112];  // gru:64 | prod: WT 6528 + xs 1584 | U: 2016
  const int tid = threadIdx.x;

  if (blockIdx.x < Bn) {
    __builtin_amdgcn_s_setprio(1);      // favor the serial pole (r8 win)
    gru_body<true>(GI, W_hh, b_hh, hs, smem, blockIdx.x, tid, flags);
    __builtin_amdgcn_s_setprio(0);
    return;
  }

  if (blockIdx.x < Bn + NPROD) {
    // ---------------- gi producer ----------------
    const int pid = blockIdx.x - Bn;
    const int tc  = pid / (Bn * 3);           // tc-major
    const int rr  = pid - tc * (Bn * 3);
    const int b   = rr / 3;
    const int g   = rr - b * 3;               // gate block: rows g*64..g*64+63
    float* WT = smem;                         // [96][68]  (stride 68, 16B-ok)
    float* xs = smem + 6528;                  // [1584]

    const int nt   = min(32, NSn - tc * 32);
    const int span = (nt - 1) * 48 + 96;
    for (int i = tid; i < 1584; i += 64)
      xs[i] = (i < span) ? x[(size_t)b * Tn + (size_t)tc * 1536 + i] : 0.0f;
    // W gate-slice: 64 rows x 96 k -> WT[k][row]; f4 global reads (96%4==0
    // keeps each quad inside one row)
    for (int e4 = tid * 4; e4 < 64 * 96; e4 += 64 * 4) {
      f4 v = *(const f4*)&W_ih[(size_t)g * 64 * 96 + e4];
      const int row = e4 / 96, k = e4 - row * 96;
#pragma unroll
      for (int c = 0; c < 4; ++c) WT[(k + c) * 68 + row] = v[c];
    }
    __builtin_amdgcn_wave_barrier();
    asm volatile("s_waitcnt lgkmcnt(0)" ::: "memory");

    const int jq = tid & 15;    // j-quad within gate block
    const int tg = tid >> 4;    // t-group (8 t each)
    const int j0 = jq * 4;

    float acc[8][4];
#pragma unroll
    for (int u = 0; u < 8; ++u)
#pragma unroll
      for (int jj = 0; jj < 4; ++jj) acc[u][jj] = b_ih[g * 64 + j0 + jj];

    for (int kc = 0; kc < 96; kc += 4) {
      f4 wq[4];
#pragma unroll
      for (int kk = 0; kk < 4; ++kk)
        wq[kk] = *(const f4*)&WT[(kc + kk) * 68 + j0];
      f4 xq[8];
#pragma unroll
      for (int u = 0; u < 8; ++u)
        xq[u] = *(const f4*)&xs[(tg * 8 + u) * 48 + kc];
      // k = kc..kc+3 ascending per acc => overall k 0..95 ascending:
      // bitwise-identical to the r0 gi accumulation.
#pragma unroll
      for (int u = 0; u < 8; ++u) {
#pragma unroll
        for (int kk = 0; kk < 4; ++kk) {
          const float xv = xq[u][kk];
          acc[u][0] = fmaf(xv, wq[kk][0], acc[u][0]);
          acc[u][1] = fmaf(xv, wq[kk][1], acc[u][1]);
          acc[u][2] = fmaf(xv, wq[kk][2], acc[u][2]);
          acc[u][3] = fmaf(xv, wq[kk][3], acc[u][3]);
        }
      }
    }

#pragma unroll
    for (int u = 0; u < 8; ++u) {
      const int tl = tg * 8 + u;
      if (tl < nt) {
        float4 st = make_float4(acc[u][0], acc[u][1], acc[u][2], acc[u][3]);
        *(float4*)&GI[(size_t)(b * NSn + tc * 32 + tl) * G3n + g * 64 + j0] = st;
      }
    }
    __threadfence();   // GI stores agent-visible before the flag
    if (tid == 0)
      __hip_atomic_fetch_add(&flags[b * 32 + tc], 1u, __ATOMIC_RELEASE,
                             __HIP_MEMORY_SCOPE_AGENT);
    return;
  }

  // ---------------- U filler (r4-proven) ----------------
  const int ub = blockIdx.x - Bn - NPROD;
  const int b  = ub / NCH;
  const int ch = ub % NCH;
  const int fA = ch * UCHUNK;
  const int fE = min(fA + UCHUNK, NFn);
  float* xu = smem;

  const int nsamp = (fE - fA - 1) * 16 + 32;
  for (int i = tid; i < nsamp; i += 64)
    xu[i] = x[(size_t)b * Tn + fA * 16 + i];

  f4 w1f[8];
#pragma unroll
  for (int i = 0; i < 8; ++i)
    w1f[i] = *(const f4*)&W1[(size_t)tid * 64 + 4 * i];
  const float bo = b1[tid];
  __builtin_amdgcn_wave_barrier();
  asm volatile("s_waitcnt lgkmcnt(0)" ::: "memory");

  float* Up = U + ((size_t)b * NFn) * GHn + tid;
  for (int f = fA; f < fE; ++f) {
    const f4* xq2 = (const f4*)&xu[(f - fA) * 16];
    float a0 = bo, a1 = 0.f, a2 = 0.f, a3 = 0.f;
#pragma unroll
    for (int i = 0; i < 8; ++i) {
      f4 xv = xq2[i];
      a0 = fmaf(xv[0], w1f[i][0], a0);
      a1 = fmaf(xv[1], w1f[i][1], a1);
      a2 = fmaf(xv[2], w1f[i][2], a2);
      a3 = fmaf(xv[3], w1f[i][3], a3);
    }
    Up[(size_t)f * GHn] = (a0 + a1) + (a2 + a3);
  }
}

// ---------------------------------------------------------------------------
// d_kernel: d[b,ts,o] = (c_s @ W1_cond^T), c_s = hs @ W_cs^T + b_cs  (proven)
// ---------------------------------------------------------------------------
__global__ __launch_bounds__(256) void d_kernel(const float* __restrict__ hs,
                                                const float* __restrict__ W_cs,
                                                const float* __restrict__ b_cs,
                                                const float* __restrict__ W1,
                                                float* __restrict__ d) {
  __shared__ __align__(16) float WcT[64 * 36];   // [k][i] stride 36
  __shared__ __align__(16) float W1cT[32 * 68];  // [i][o] stride 68
  __shared__ __align__(16) float hsl[32 * 65];   // [t][k] stride 65
  __shared__ __align__(16) float cloc[32 * 36];  // [t][i] stride 36
  __shared__ __align__(16) float bcs[32];
  const int tile = blockIdx.x;   // 0..31
  const int b    = blockIdx.y;
  const int t0   = tile * 32;
  const int nt   = min(32, NSn - t0);
  const int tid  = threadIdx.x;

  for (int e = tid; e < 32 * 64; e += 256) {
    int i = e >> 6, k = e & 63;
    WcT[k * 36 + i] = W_cs[e];
  }
  for (int e = tid; e < 64 * 32; e += 256) {
    int o = e >> 5, i = e & 31;
    W1cT[i * 68 + o] = W1[(size_t)o * 64 + 32 + i];
  }
  for (int e = tid; e < nt * 64; e += 256) {
    int t = e >> 6, k = e & 63;
    hsl[t * 65 + k] = hs[((size_t)b * NSn + t0 + t) * GHn + k];
  }
  if (tid < 32) bcs[tid] = b_cs[tid];
  __syncthreads();

  {
    const int iq = tid & 7;
    const int t  = tid >> 3;
    if (t < nt) {
      float4 acc = *(const float4*)&bcs[iq * 4];
      const float* hr = &hsl[t * 65];
#pragma unroll 4
      for (int k = 0; k < 64; ++k) {
        float hv = hr[k];
        float4 w = *(const float4*)&WcT[k * 36 + iq * 4];
        acc.x = fmaf(w.x, hv, acc.x);
        acc.y = fmaf(w.y, hv, acc.y);
        acc.z = fmaf(w.z, hv, acc.z);
        acc.w = fmaf(w.w, hv, acc.w);
      }
      *(float4*)&cloc[t * 36 + iq * 4] = acc;
    }
  }
  __syncthreads();

  for (int it = tid; it < 32 * 16; it += 256) {
    const int oq = it & 15;
    const int t  = it >> 4;
    if (t < nt) {
      float a0 = 0.f, a1 = 0.f, a2 = 0.f, a3 = 0.f;
      const float* cr = &cloc[t * 36];
#pragma unroll 4
      for (int i = 0; i < 32; ++i) {
        float cv = cr[i];
        float4 w = *(const float4*)&W1cT[i * 68 + oq * 4];
        a0 = fmaf(w.x, cv, a0);
        a1 = fmaf(w.y, cv, a1);
        a2 = fmaf(w.z, cv, a2);
        a3 = fmaf(w.w, cv, a3);
      }
      float4 st = make_float4(a0, a1, a2, a3);
      *(float4*)&d[((size_t)b * NSn + t0 + t) * GHn + oq * 4] = st;
    }
  }
}

// ---------------------------------------------------------------------------
// out2: h = relu(U + d[ts]), y = h@W2^T + b2, overlap-add  (proven).
// NOTE: overwrites ALL of `out`, including the 16KB flag region at its head.
// ---------------------------------------------------------------------------
__global__ __launch_bounds__(256) void out2_kernel(const float* __restrict__ U,
                                                   const float* __restrict__ d,
                                                   const float* __restrict__ W2,
                                                   const float* __restrict__ b2,
                                                   float* __restrict__ out) {
  __shared__ __align__(16) float h1loc[33 * 68];
  __shared__ __align__(16) float W2T[64 * 36];
  __shared__ __align__(16) float yloc[33 * 32];
  __shared__ __align__(16) float dloc[12][68];
  __shared__ __align__(16) float bb2[32];

  const int fb  = blockIdx.x;
  const int b   = blockIdx.y;
  const int f0  = fb * 32;
  const int nf  = min(33, NFn - f0);
  const int tid = threadIdx.x;
  const int ts0 = max(f0 / 3 - 1, 0);

  for (int e = tid; e < 32 * 64; e += 256) {
    int o = e >> 6, k = e & 63;
    W2T[k * 36 + o] = W2[e];
  }
  if (tid < 32) bb2[tid] = b2[tid];
  for (int e = tid; e < 12 * 64; e += 256) {
    int ti = e >> 6, o = e & 63;
    int ts = min(ts0 + ti, NSn - 1);
    dloc[ti][o] = d[((size_t)b * NSn + ts) * GHn + o];
  }
  __syncthreads();

  for (int it = tid; it < 33 * 16; it += 256) {
    const int lf = it >> 4, oq = it & 15;
    const int f  = f0 + lf;
    f4 s = {0.f, 0.f, 0.f, 0.f};
    if (f < NFn) {
      f4 u  = *(const f4*)&U[((size_t)b * NFn + f) * GHn + oq * 4];
      const int ti = max(f / 3 - 1, 0) - ts0;
      f4 dv = *(const f4*)&dloc[ti][oq * 4];
      s = u + dv;
#pragma unroll
      for (int c = 0; c < 4; ++c) s[c] = fmaxf(s[c], 0.f);
    }
    *(f4*)&h1loc[lf * 68 + oq * 4] = s;
  }
  __syncthreads();

  for (int it = tid; it < 33 * 8; it += 256) {
    const int lf = it >> 3, oq = it & 7;
    float4 acc = *(const float4*)&bb2[oq * 4];
    const float* hr = &h1loc[lf * 68];
#pragma unroll 4
    for (int k = 0; k < 64; ++k) {
      float hv = hr[k];
      float4 w = *(const float4*)&W2T[k * 36 + oq * 4];
      acc.x = fmaf(w.x, hv, acc.x);
      acc.y = fmaf(w.y, hv, acc.y);
      acc.z = fmaf(w.z, hv, acc.z);
      acc.w = fmaf(w.w, hv, acc.w);
    }
    *(float4*)&yloc[lf * 32 + oq * 4] = acc;
  }
  __syncthreads();

  const int s0 = f0 * 16 + 16;
  const int s1 = min(s0 + 512, Tn);
  for (int s = s0 + tid; s < s1; s += 256) {
    int f1  = s >> 4;
    int o1  = s & 15;
    int lf1 = f1 - f0;
    float v = yloc[(lf1 - 1) * 32 + o1 + 16];
    if (lf1 < nf) v += yloc[lf1 * 32 + o1];
    out[(size_t)b * Tn + s] = v;
  }
  if (fb == 0 && tid < 16) out[(size_t)b * Tn + tid] = yloc[tid];
}

// ---------------------------------------------------------------------------
// Fallback kernels (small-ws only): round-0 proven pipeline
// ---------------------------------------------------------------------------
__global__ __launch_bounds__(192) void gi_kernel(const float* __restrict__ x,
                                                 const float* __restrict__ W_ih,
                                                 const float* __restrict__ b_ih,
                                                 float* __restrict__ GI) {
  __shared__ __align__(16) float WT[48 * 196];
  __shared__ __align__(16) float xs[1584];
  const int tile = blockIdx.x;
  const int b    = blockIdx.y;
  const int t0   = tile * 32;
  const int nt   = min(32, NSn - t0);
  const int tid  = threadIdx.x;

  const int span = (nt - 1) * 48 + 96;
  for (int i = tid; i < 1584; i += 192)
    xs[i] = (i < span) ? x[(size_t)b * Tn + t0 * 48 + i] : 0.0f;

  const int jq = tid % 48;
  const int tg = tid / 48;
  const int j0 = jq * 4;

  float acc[8][4];
#pragma unroll
  for (int u = 0; u < 8; ++u)
#pragma unroll
    for (int jj = 0; jj < 4; ++jj) acc[u][jj] = b_ih[j0 + jj];

  for (int half = 0; half < 2; ++half) {
    __syncthreads();
    for (int e = tid; e < 192 * 48; e += 192) {
      int j = e / 48, k = e % 48;
      WT[k * 196 + j] = W_ih[j * 96 + half * 48 + k];
    }
    __syncthreads();
    for (int k = 0; k < 48; ++k) {
      float4 w = *(const float4*)&WT[k * 196 + j0];
#pragma unroll
      for (int u = 0; u < 8; ++u) {
        float xv = xs[(tg * 8 + u) * 48 + half * 48 + k];
        acc[u][0] = fmaf(xv, w.x, acc[u][0]);
        acc[u][1] = fmaf(xv, w.y, acc[u][1]);
        acc[u][2] = fmaf(xv, w.z, acc[u][2]);
        acc[u][3] = fmaf(xv, w.w, acc[u][3]);
      }
    }
  }

#pragma unroll
  for (int u = 0; u < 8; ++u) {
    int tl = tg * 8 + u;
    if (tl < nt) {
      float4 st = make_float4(acc[u][0], acc[u][1], acc[u][2], acc[u][3]);
      *(float4*)&GI[(size_t)(b * NSn + t0 + tl) * G3n + j0] = st;
    }
  }
}

__global__ __attribute__((amdgpu_flat_work_group_size(64, 64),
                          amdgpu_waves_per_eu(1, 1),
                          amdgpu_num_vgpr(256)))
void gru_kernel(const float* __restrict__ GI,
                const float* __restrict__ W_hh,
                const float* __restrict__ b_hh,
                float* __restrict__ hs) {
  __shared__ __align__(16) float hbuf[64];
  gru_body<false>(GI, W_hh, b_hh, hs, hbuf, blockIdx.x, threadIdx.x, nullptr);
}

__global__ __launch_bounds__(256) void cs_kernel(const float* __restrict__ hs,
                                                 const float* __restrict__ W_cs,
                                                 const float* __restrict__ b_cs,
                                                 float* __restrict__ cs) {
  __shared__ __align__(16) float WcT[64 * 36];
  __shared__ __align__(16) float hsl[32 * 65];
  __shared__ __align__(16) float bcs[32];
  const int tile = blockIdx.x;
  const int b    = blockIdx.y;
  const int t0   = tile * 32;
  const int nt   = min(32, NSn - t0);
  const int tid  = threadIdx.x;

  for (int e = tid; e < 32 * 64; e += 256) {
    int i = e >> 6, k = e & 63;
    WcT[k * 36 + i] = W_cs[e];
  }
  for (int e = tid; e < nt * 64; e += 256) {
    int t = e >> 6, k = e & 63;
    hsl[t * 65 + k] = hs[((size_t)b * NSn + t0 + t) * GHn + k];
  }
  if (tid < 32) bcs[tid] = b_cs[tid];
  __syncthreads();

  const int oq = tid & 7;
  const int t  = tid >> 3;
  if (t < nt) {
    float4 acc = *(const float4*)&bcs[oq * 4];
    const float* hr = &hsl[t * 65];
#pragma unroll 4
    for (int k = 0; k < 64; ++k) {
      float hv = hr[k];
      float4 w = *(const float4*)&WcT[k * 36 + oq * 4];
      acc.x = fmaf(w.x, hv, acc.x);
      acc.y = fmaf(w.y, hv, acc.y);
      acc.z = fmaf(w.z, hv, acc.z);
      acc.w = fmaf(w.w, hv, acc.w);
    }
    *(float4*)&cs[((size_t)b * NSn + t0 + t) * 32 + oq * 4] = acc;
  }
}

__global__ __launch_bounds__(256) void out_kernel(const float* __restrict__ x,
                                                  const float* __restrict__ cs,
                                                  const float* __restrict__ W1,
                                                  const float* __restrict__ b1,
                                                  const float* __restrict__ W2,
                                                  const float* __restrict__ b2,
                                                  float* __restrict__ out) {
  __shared__ __align__(16) float A[33 * 65];
  __shared__ __align__(16) float W1T[64 * 68];
  __shared__ __align__(16) float W2T[64 * 36];
  __shared__ __align__(16) float h1loc[33 * 65];
  __shared__ __align__(16) float yloc[33 * 32];
  __shared__ __align__(16) float bb1[64];
  __shared__ __align__(16) float bb2[32];

  const int fb  = blockIdx.x;
  const int b   = blockIdx.y;
  const int f0  = fb * 32;
  const int nf  = min(33, NFn - f0);
  const int tid = threadIdx.x;

  for (int e = tid; e < 64 * 64; e += 256) {
    int o = e >> 6, k = e & 63;
    W1T[k * 68 + o] = W1[e];
  }
  for (int e = tid; e < 32 * 64; e += 256) {
    int o = e >> 6, k = e & 63;
    W2T[k * 36 + o] = W2[e];
  }
  if (tid < 64) bb1[tid] = b1[tid];
  if (tid < 32) bb2[tid] = b2[tid];

  for (int e = tid; e < 33 * 32; e += 256) {
    int lf = e >> 5, k = e & 31;
    int g = (f0 + lf) * 16 + k;
    A[lf * 65 + k] = (lf < nf && g < Tn) ? x[(size_t)b * Tn + g] : 0.0f;
  }
  for (int e = tid; e < 33 * 32; e += 256) {
    int lf = e >> 5, k = e & 31;
    int ts = max((f0 + lf) / 3 - 1, 0);
    A[lf * 65 + 32 + k] = (lf < nf) ? cs[((size_t)b * NSn + ts) * 32 + k] : 0.0f;
  }
  __syncthreads();

  for (int it = tid; it < 33 * 16; it += 256) {
    int lf = it >> 4, oq = it & 15;
    float4 acc = *(const float4*)&bb1[oq * 4];
    const float* ar = &A[lf * 65];
#pragma unroll 4
    for (int k = 0; k < 64; ++k) {
      float av = ar[k];
      float4 w = *(const float4*)&W1T[k * 68 + oq * 4];
      acc.x = fmaf(w.x, av, acc.x);
      acc.y = fmaf(w.y, av, acc.y);
      acc.z = fmaf(w.z, av, acc.z);
      acc.w = fmaf(w.w, av, acc.w);
    }
    acc.x = fmaxf(acc.x, 0.0f); acc.y = fmaxf(acc.y, 0.0f);
    acc.z = fmaxf(acc.z, 0.0f); acc.w = fmaxf(acc.w, 0.0f);
    *(float4*)&h1loc[lf * 65 + oq * 4] = acc;
  }
  __syncthreads();

  for (int it = tid; it < 33 * 8; it += 256) {
    int lf = it >> 3, oq = it & 7;
    float4 acc = *(const float4*)&bb2[oq * 4];
    const float* hr = &h1loc[lf * 65];
#pragma unroll 4
    for (int k = 0; k < 64; ++k) {
      float hv = hr[k];
      float4 w = *(const float4*)&W2T[k * 36 + oq * 4];
      acc.x = fmaf(w.x, hv, acc.x);
      acc.y = fmaf(w.y, hv, acc.y);
      acc.z = fmaf(w.z, hv, acc.z);
      acc.w = fmaf(w.w, hv, acc.w);
    }
    *(float4*)&yloc[lf * 32 + oq * 4] = acc;
  }
  __syncthreads();

  const int s0 = f0 * 16 + 16;
  const int s1 = min(s0 + 512, Tn);
  for (int s = s0 + tid; s < s1; s += 256) {
    int f1  = s >> 4;
    int o1  = s & 15;
    int lf1 = f1 - f0;
    float v = yloc[(lf1 - 1) * 32 + o1 + 16];
    if (lf1 < nf) v += yloc[lf1 * 32 + o1];
    out[(size_t)b * Tn + s] = v;
  }
  if (fb == 0 && tid < 16) out[(size_t)b * Tn + tid] = yloc[tid];
}

// ---------------------------------------------------------------------------
extern "C" void kernel_launch(void* const* d_in, const int* in_sizes, int n_in,
                              void* d_out, int out_size, void* d_ws, size_t ws_size,
                              hipStream_t stream) {
  const float* x    = (const float*)d_in[0];
  const float* W_ih = (const float*)d_in[1];
  const float* W_hh = (const float*)d_in[2];
  const float* b_ih = (const float*)d_in[3];
  const float* b_hh = (const float*)d_in[4];
  const float* W_cs = (const float*)d_in[5];
  const float* b_cs = (const float*)d_in[6];
  const float* W1   = (const float*)d_in[7];
  const float* b1   = (const float*)d_in[8];
  const float* W2   = (const float*)d_in[9];
  const float* b2   = (const float*)d_in[10];
  float* out = (float*)d_out;

  const size_t giN = (size_t)Bn * NSn * G3n;   // 98.2 MB
  const size_t hsN = (size_t)Bn * NSn * GHn;   // 32.7 MB
  const size_t uN  = (size_t)Bn * NFn * GHn;   // 98.3 MB

  float* GI = (float*)d_ws;
  float* hs = GI + giN;

  if (ws_size >= (giN + hsN + uN) * sizeof(float)) {
    // Fast path: gi producers + polling gru + U, all in one grid.
    float* U = hs + hsN;
    float* d = GI;                             // GI dead after fat3
    // flags: first 16KB of `out` (r6 precedent; out2 overwrites all of out).
    unsigned int* flags = (unsigned int*)out;
    hipMemsetAsync(out, 0, (size_t)Bn * 32 * sizeof(unsigned int), stream);

    fat3_kernel<<<Bn + NPROD + Bn * NCH, 64, 0, stream>>>(
        x, W_ih, b_ih, W_hh, b_hh, W1, b1, GI, hs, U, flags);
    d_kernel<<<dim3(32, Bn), 256, 0, stream>>>(hs, W_cs, b_cs, W1, d);
    out2_kernel<<<dim3(94, Bn), 256, 0, stream>>>(U, d, W2, b2, out);
  } else {
    // Small-ws fallback: round-0 proven pipeline.
    float* cs = GI;
    gi_kernel<<<dim3(32, Bn), 192, 0, stream>>>(x, W_ih, b_ih, GI);
    gru_kernel<<<Bn, 64, 0, stream>>>(GI, W_hh, b_hh, hs);
    cs_kernel<<<dim3(32, Bn), 256, 0, stream>>>(hs, W_cs, b_cs, cs);
    out_kernel<<<dim3(94, Bn), 256, 0, stream>>>(x, cs, W1, b1, W2, b2, out);
  }
}

// Round 11
// 1142.518 us; speedup vs baseline: 1.0912x; 1.0912x over previous
//
#include <hip/hip_runtime.h>

// Problem constants
constexpr int Bn  = 128;
constexpr int Tn  = 48000;
constexpr int NFn = 2999;   // fast frames
constexpr int NSn = 999;    // slow frames
constexpr int G3n = 192;    // 3*GH
constexpr int GHn = 64;

typedef float f2 __attribute__((ext_vector_type(2)));
typedef float f4 __attribute__((ext_vector_type(4)));

__device__ __forceinline__ float fsigmoid(float v) {
  return __fdividef(1.0f, 1.0f + __expf(-v));
}
__device__ __forceinline__ float ftanh_f(float v) {
  return 1.0f - __fdividef(2.0f, __expf(2.0f * v) + 1.0f);
}

// ---------------------------------------------------------------------------
// GRU body (round-0 proven, 485us). POLL=true: wait on flags[b*32+tc] >= 1
// (one flag per (b, 32-step chunk), set by a full r0-gi producer block).
// r6/r10-proven machinery: acquire agent-scope load + threadfence on the
// consumer; __syncthreads + threadfence + release fetch_add on the producer.
// ---------------------------------------------------------------------------
template <bool POLL>
__device__ __forceinline__ void gru_body(const float* __restrict__ GI,
                                         const float* __restrict__ W_hh,
                                         const float* __restrict__ b_hh,
                                         float* __restrict__ hs,
                                         float* hbuf, int b, int j,
                                         unsigned int* flags) {
  f2 wr2[32], wz2[32], wn2[32];
  const f2* Wr = (const f2*)(W_hh + (size_t)j * 64);
  const f2* Wz = (const f2*)(W_hh + (size_t)(j + 64) * 64);
  const f2* Wn = (const f2*)(W_hh + (size_t)(j + 128) * 64);
#pragma unroll
  for (int q = 0; q < 32; ++q) { wr2[q] = Wr[q]; wz2[q] = Wz[q]; wn2[q] = Wn[q]; }
  // Opaque to the compiler => cannot re-load from memory inside the loop.
#pragma unroll
  for (int q = 0; q < 32; ++q) {
    asm volatile("" : "+v"(wr2[q]));
    asm volatile("" : "+v"(wz2[q]));
    asm volatile("" : "+v"(wn2[q]));
  }
  const float br = b_hh[j], bz = b_hh[j + 64], bn = b_hh[j + 128];

  unsigned int* fl = POLL ? (flags + b * 32) : nullptr;
  int cur_tc = 0;
  if (POLL) {
    if (j == 0) {
      while (__hip_atomic_load(&fl[0], __ATOMIC_ACQUIRE,
                               __HIP_MEMORY_SCOPE_AGENT) < 1u)
        __builtin_amdgcn_s_sleep(4);
    }
    __builtin_amdgcn_wave_barrier();
    __threadfence();
  }

  hbuf[j] = 0.0f;
  float hj = 0.0f;
  __builtin_amdgcn_wave_barrier();

  const float* gp = GI + (size_t)b * NSn * G3n;
  float* hsp = hs + (size_t)b * NSn * GHn;

  // distance-2 prefetch ring
  float pr0, pr1, pr2, pz0, pz1, pz2, pn0, pn1, pn2;
  pr0 = gp[0 * G3n + j];       pz0 = gp[0 * G3n + 64 + j];  pn0 = gp[0 * G3n + 128 + j];
  pr1 = gp[1 * G3n + j];       pz1 = gp[1 * G3n + 64 + j];  pn1 = gp[1 * G3n + 128 + j];

  for (int t = 0; t < NSn; ++t) {
    const int tn = min(t + 2, NSn - 1);
    if (POLL) {
      const int tc2 = tn >> 5;
      if (tc2 != cur_tc) {
        if (j == 0) {
          while (__hip_atomic_load(&fl[tc2], __ATOMIC_ACQUIRE,
                                   __HIP_MEMORY_SCOPE_AGENT) < 1u)
            __builtin_amdgcn_s_sleep(4);
        }
        __builtin_amdgcn_wave_barrier();
        __threadfence();
        cur_tc = tc2;
      }
    }
    const size_t off = (size_t)tn * G3n;
    pr2 = gp[off + j];
    pz2 = gp[off + 64 + j];
    pn2 = gp[off + 128 + j];

    const f2* h2 = (const f2*)hbuf;
    f2 ar0 = {0.f, 0.f}, ar1 = {0.f, 0.f}, ar2 = {0.f, 0.f}, ar3 = {0.f, 0.f};
    f2 az0 = {0.f, 0.f}, az1 = {0.f, 0.f}, az2 = {0.f, 0.f}, az3 = {0.f, 0.f};
    f2 an0 = {0.f, 0.f}, an1 = {0.f, 0.f}, an2 = {0.f, 0.f}, an3 = {0.f, 0.f};
#pragma unroll
    for (int q = 0; q < 8; ++q) {
      f2 h0 = h2[q * 4 + 0], h1 = h2[q * 4 + 1], h2v = h2[q * 4 + 2], h3 = h2[q * 4 + 3];
      ar0 += wr2[q * 4 + 0] * h0; ar1 += wr2[q * 4 + 1] * h1;
      ar2 += wr2[q * 4 + 2] * h2v; ar3 += wr2[q * 4 + 3] * h3;
      az0 += wz2[q * 4 + 0] * h0; az1 += wz2[q * 4 + 1] * h1;
      az2 += wz2[q * 4 + 2] * h2v; az3 += wz2[q * 4 + 3] * h3;
      an0 += wn2[q * 4 + 0] * h0; an1 += wn2[q * 4 + 1] * h1;
      an2 += wn2[q * 4 + 2] * h2v; an3 += wn2[q * 4 + 3] * h3;
    }
    f2 sr = (ar0 + ar1) + (ar2 + ar3);
    f2 sz = (az0 + az1) + (az2 + az3);
    f2 sn = (an0 + an1) + (an2 + an3);

    float r = fsigmoid(pr0 + br + sr.x + sr.y);
    float z = fsigmoid(pz0 + bz + sz.x + sz.y);
    float n = ftanh_f(fmaf(r, bn + sn.x + sn.y, pn0));
    float hn = fmaf(z, hj - n, n);          // (1-z)*n + z*h

    __builtin_amdgcn_wave_barrier();
    hbuf[j] = hn;
    __builtin_amdgcn_wave_barrier();
    hj = hn;
    hsp[(size_t)t * GHn + j] = hn;

    pr0 = pr1; pr1 = pr2;
    pz0 = pz1; pz1 = pz2;
    pn0 = pn1; pn1 = pn2;
  }
}

// ---------------------------------------------------------------------------
// FAT4 kernel, 192 threads/block, NO waves_per_eu cap.
// r10 post-mortem: 64-thr/1-wave-per-SIMD producers ran ~10x slower than
// modeled in BOTH persistent (r6) and block-per-tile (r10) forms — a lone
// wave cannot hide staging latency. Fix: producers are the EXACT r0 gi
// block (192 thr, 3 waves, measured 27us/block at natural occupancy).
//  [0,128):        gru wave 0 (setprio 1, POLL); waves 1-2 exit.
//  [128,128+4096): gi tile (b, tc) tc-MAJOR — r0 code verbatim + flag.
//  [4224,5248):    U filler, r9-verified 3-wave form (wave w = chunk).
// num_vgpr(256) keeps gru weights resident AND caps co-tenancy at 2
// waves/SIMD (bounds gru-SIMD interference). Deadlock-free in any dispatch
// order: only gru waits; producers/U never wait; 128 waiters << slots.
// ---------------------------------------------------------------------------
constexpr int UCHUNK = 125;
constexpr int NGI    = Bn * 32;   // 4096 gi tiles
constexpr int NU     = Bn * 8;    // 1024 U blocks x 3 waves = 24 chunks/b

__global__ __attribute__((amdgpu_flat_work_group_size(192, 192),
                          amdgpu_num_vgpr(256)))
void fat4_kernel(const float* __restrict__ x,
                 const float* __restrict__ W_ih,
                 const float* __restrict__ b_ih,
                 const float* __restrict__ W_hh,
                 const float* __restrict__ b_hh,
                 const float* __restrict__ W1,
                 const float* __restrict__ b1,
                 float* __restrict__ GI,
                 float* __restrict__ hs,
                 float* __restrict__ U,
                 unsigned int* __restrict__ flags) {
  __shared__ __align__(16) float smem[10992];   // 43968B: gi WT+xs | U 3x2016 | gru 64
  const int tid = threadIdx.x;

  if (blockIdx.x < Bn) {
    // ---------------- gru ----------------
    if (tid >= 64) return;               // waves 1-2 release their slots
    __builtin_amdgcn_s_setprio(1);       // favor the serial pole (r8 win)
    gru_body<true>(GI, W_hh, b_hh, hs, smem, blockIdx.x, tid, flags);
    __builtin_amdgcn_s_setprio(0);
    return;
  }

  if (blockIdx.x < Bn + NGI) {
    // ---------------- gi producer: EXACT r0 gi block, tc-major ----------------
    const int pid = blockIdx.x - Bn;
    const int tc  = pid >> 7;            // tc-major: chunk 0 for all b first
    const int b   = pid & 127;
    const int t0  = tc * 32;
    const int nt  = min(32, NSn - t0);
    float* WT = smem;                    // [48][196] k-half staging
    float* xs = smem + 48 * 196;         // [1584]

    const int span = (nt - 1) * 48 + 96;
    for (int i = tid; i < 1584; i += 192)
      xs[i] = (i < span) ? x[(size_t)b * Tn + t0 * 48 + i] : 0.0f;

    const int jq = tid % 48;
    const int tg = tid / 48;
    const int j0 = jq * 4;

    float acc[8][4];
#pragma unroll
    for (int u = 0; u < 8; ++u)
#pragma unroll
      for (int jj = 0; jj < 4; ++jj) acc[u][jj] = b_ih[j0 + jj];

    for (int half = 0; half < 2; ++half) {
      __syncthreads();
      for (int e = tid; e < 192 * 48; e += 192) {
        int j = e / 48, k = e % 48;
        WT[k * 196 + j] = W_ih[j * 96 + half * 48 + k];
      }
      __syncthreads();
      for (int k = 0; k < 48; ++k) {
        float4 w = *(const float4*)&WT[k * 196 + j0];
#pragma unroll
        for (int u = 0; u < 8; ++u) {
          float xv = xs[(tg * 8 + u) * 48 + half * 48 + k];
          acc[u][0] = fmaf(xv, w.x, acc[u][0]);
          acc[u][1] = fmaf(xv, w.y, acc[u][1]);
          acc[u][2] = fmaf(xv, w.z, acc[u][2]);
          acc[u][3] = fmaf(xv, w.w, acc[u][3]);
        }
      }
    }

#pragma unroll
    for (int u = 0; u < 8; ++u) {
      int tl = tg * 8 + u;
      if (tl < nt) {
        float4 st = make_float4(acc[u][0], acc[u][1], acc[u][2], acc[u][3]);
        *(float4*)&GI[(size_t)(b * NSn + t0 + tl) * G3n + j0] = st;
      }
    }
    __syncthreads();   // all 192 threads' GI stores issued
    __threadfence();   // agent-visible before the flag
    if (tid == 0)
      __hip_atomic_fetch_add(&flags[b * 32 + tc], 1u, __ATOMIC_RELEASE,
                             __HIP_MEMORY_SCOPE_AGENT);
    return;
  }

  // ---------------- U filler (r9-verified 3-wave form) ----------------
  const int wid  = tid >> 6;
  const int lane = tid & 63;
  const int ub = blockIdx.x - Bn - NGI;  // 0..1023
  const int b  = ub >> 3;
  const int ch = (ub & 7) * 3 + wid;     // 0..23
  const int fA = ch * UCHUNK;
  const int fE = min(fA + UCHUNK, NFn);
  float* xu = smem + wid * 2016;
  const int nsamp = (fE - fA - 1) * 16 + 32;
  for (int i = lane; i < nsamp; i += 64)
    xu[i] = x[(size_t)b * Tn + fA * 16 + i];
  f4 w1f[8];
#pragma unroll
  for (int i = 0; i < 8; ++i)
    w1f[i] = *(const f4*)&W1[(size_t)lane * 64 + 4 * i];
  const float bo = b1[lane];
  __builtin_amdgcn_wave_barrier();
  asm volatile("s_waitcnt lgkmcnt(0)" ::: "memory");

  float* Up = U + ((size_t)b * NFn) * GHn + lane;
  for (int f = fA; f < fE; ++f) {
    const f4* xq2 = (const f4*)&xu[(f - fA) * 16];
    float a0 = bo, a1 = 0.f, a2 = 0.f, a3 = 0.f;
#pragma unroll
    for (int i = 0; i < 8; ++i) {
      f4 xv = xq2[i];
      a0 = fmaf(xv[0], w1f[i][0], a0);
      a1 = fmaf(xv[1], w1f[i][1], a1);
      a2 = fmaf(xv[2], w1f[i][2], a2);
      a3 = fmaf(xv[3], w1f[i][3], a3);
    }
    Up[(size_t)f * GHn] = (a0 + a1) + (a2 + a3);
  }
}

// ---------------------------------------------------------------------------
// d_kernel: d[b,ts,o] = (c_s @ W1_cond^T), c_s = hs @ W_cs^T + b_cs  (proven)
// ---------------------------------------------------------------------------
__global__ __launch_bounds__(256) void d_kernel(const float* __restrict__ hs,
                                                const float* __restrict__ W_cs,
                                                const float* __restrict__ b_cs,
                                                const float* __restrict__ W1,
                                                float* __restrict__ d) {
  __shared__ __align__(16) float WcT[64 * 36];   // [k][i] stride 36
  __shared__ __align__(16) float W1cT[32 * 68];  // [i][o] stride 68
  __shared__ __align__(16) float hsl[32 * 65];   // [t][k] stride 65
  __shared__ __align__(16) float cloc[32 * 36];  // [t][i] stride 36
  __shared__ __align__(16) float bcs[32];
  const int tile = blockIdx.x;   // 0..31
  const int b    = blockIdx.y;
  const int t0   = tile * 32;
  const int nt   = min(32, NSn - t0);
  const int tid  = threadIdx.x;

  for (int e = tid; e < 32 * 64; e += 256) {
    int i = e >> 6, k = e & 63;
    WcT[k * 36 + i] = W_cs[e];
  }
  for (int e = tid; e < 64 * 32; e += 256) {
    int o = e >> 5, i = e & 31;
    W1cT[i * 68 + o] = W1[(size_t)o * 64 + 32 + i];
  }
  for (int e = tid; e < nt * 64; e += 256) {
    int t = e >> 6, k = e & 63;
    hsl[t * 65 + k] = hs[((size_t)b * NSn + t0 + t) * GHn + k];
  }
  if (tid < 32) bcs[tid] = b_cs[tid];
  __syncthreads();

  {
    const int iq = tid & 7;
    const int t  = tid >> 3;
    if (t < nt) {
      float4 acc = *(const float4*)&bcs[iq * 4];
      const float* hr = &hsl[t * 65];
#pragma unroll 4
      for (int k = 0; k < 64; ++k) {
        float hv = hr[k];
        float4 w = *(const float4*)&WcT[k * 36 + iq * 4];
        acc.x = fmaf(w.x, hv, acc.x);
        acc.y = fmaf(w.y, hv, acc.y);
        acc.z = fmaf(w.z, hv, acc.z);
        acc.w = fmaf(w.w, hv, acc.w);
      }
      *(float4*)&cloc[t * 36 + iq * 4] = acc;
    }
  }
  __syncthreads();

  for (int it = tid; it < 32 * 16; it += 256) {
    const int oq = it & 15;
    const int t  = it >> 4;
    if (t < nt) {
      float a0 = 0.f, a1 = 0.f, a2 = 0.f, a3 = 0.f;
      const float* cr = &cloc[t * 36];
#pragma unroll 4
      for (int i = 0; i < 32; ++i) {
        float cv = cr[i];
        float4 w = *(const float4*)&W1cT[i * 68 + oq * 4];
        a0 = fmaf(w.x, cv, a0);
        a1 = fmaf(w.y, cv, a1);
        a2 = fmaf(w.z, cv, a2);
        a3 = fmaf(w.w, cv, a3);
      }
      float4 st = make_float4(a0, a1, a2, a3);
      *(float4*)&d[((size_t)b * NSn + t0 + t) * GHn + oq * 4] = st;
    }
  }
}

// ---------------------------------------------------------------------------
// out2: h = relu(U + d[ts]), y = h@W2^T + b2, overlap-add  (proven).
// Overwrites ALL of `out`, including the 16KB flag region at its head.
// ---------------------------------------------------------------------------
__global__ __launch_bounds__(256) void out2_kernel(const float* __restrict__ U,
                                                   const float* __restrict__ d,
                                                   const float* __restrict__ W2,
                                                   const float* __restrict__ b2,
                                                   float* __restrict__ out) {
  __shared__ __align__(16) float h1loc[33 * 68];
  __shared__ __align__(16) float W2T[64 * 36];
  __shared__ __align__(16) float yloc[33 * 32];
  __shared__ __align__(16) float dloc[12][68];
  __shared__ __align__(16) float bb2[32];

  const int fb  = blockIdx.x;
  const int b   = blockIdx.y;
  const int f0  = fb * 32;
  const int nf  = min(33, NFn - f0);
  const int tid = threadIdx.x;
  const int ts0 = max(f0 / 3 - 1, 0);

  for (int e = tid; e < 32 * 64; e += 256) {
    int o = e >> 6, k = e & 63;
    W2T[k * 36 + o] = W2[e];
  }
  if (tid < 32) bb2[tid] = b2[tid];
  for (int e = tid; e < 12 * 64; e += 256) {
    int ti = e >> 6, o = e & 63;
    int ts = min(ts0 + ti, NSn - 1);
    dloc[ti][o] = d[((size_t)b * NSn + ts) * GHn + o];
  }
  __syncthreads();

  for (int it = tid; it < 33 * 16; it += 256) {
    const int lf = it >> 4, oq = it & 15;
    const int f  = f0 + lf;
    f4 s = {0.f, 0.f, 0.f, 0.f};
    if (f < NFn) {
      f4 u  = *(const f4*)&U[((size_t)b * NFn + f) * GHn + oq * 4];
      const int ti = max(f / 3 - 1, 0) - ts0;
      f4 dv = *(const f4*)&dloc[ti][oq * 4];
      s = u + dv;
#pragma unroll
      for (int c = 0; c < 4; ++c) s[c] = fmaxf(s[c], 0.f);
    }
    *(f4*)&h1loc[lf * 68 + oq * 4] = s;
  }
  __syncthreads();

  for (int it = tid; it < 33 * 8; it += 256) {
    const int lf = it >> 3, oq = it & 7;
    float4 acc = *(const float4*)&bb2[oq * 4];
    const float* hr = &h1loc[lf * 68];
#pragma unroll 4
    for (int k = 0; k < 64; ++k) {
      float hv = hr[k];
      float4 w = *(const float4*)&W2T[k * 36 + oq * 4];
      acc.x = fmaf(w.x, hv, acc.x);
      acc.y = fmaf(w.y, hv, acc.y);
      acc.z = fmaf(w.z, hv, acc.z);
      acc.w = fmaf(w.w, hv, acc.w);
    }
    *(float4*)&yloc[lf * 32 + oq * 4] = acc;
  }
  __syncthreads();

  const int s0 = f0 * 16 + 16;
  const int s1 = min(s0 + 512, Tn);
  for (int s = s0 + tid; s < s1; s += 256) {
    int f1  = s >> 4;
    int o1  = s & 15;
    int lf1 = f1 - f0;
    float v = yloc[(lf1 - 1) * 32 + o1 + 16];
    if (lf1 < nf) v += yloc[lf1 * 32 + o1];
    out[(size_t)b * Tn + s] = v;
  }
  if (fb == 0 && tid < 16) out[(size_t)b * Tn + tid] = yloc[tid];
}

// ---------------------------------------------------------------------------
// Fallback kernels (small-ws only): round-0 proven pipeline
// ---------------------------------------------------------------------------
__global__ __launch_bounds__(192) void gi_kernel(const float* __restrict__ x,
                                                 const float* __restrict__ W_ih,
                                                 const float* __restrict__ b_ih,
                                                 float* __restrict__ GI) {
  __shared__ __align__(16) float WT[48 * 196];
  __shared__ __align__(16) float xs[1584];
  const int tile = blockIdx.x;
  const int b    = blockIdx.y;
  const int t0   = tile * 32;
  const int nt   = min(32, NSn - t0);
  const int tid  = threadIdx.x;

  const int span = (nt - 1) * 48 + 96;
  for (int i = tid; i < 1584; i += 192)
    xs[i] = (i < span) ? x[(size_t)b * Tn + t0 * 48 + i] : 0.0f;

  const int jq = tid % 48;
  const int tg = tid / 48;
  const int j0 = jq * 4;

  float acc[8][4];
#pragma unroll
  for (int u = 0; u < 8; ++u)
#pragma unroll
    for (int jj = 0; jj < 4; ++jj) acc[u][jj] = b_ih[j0 + jj];

  for (int half = 0; half < 2; ++half) {
    __syncthreads();
    for (int e = tid; e < 192 * 48; e += 192) {
      int j = e / 48, k = e % 48;
      WT[k * 196 + j] = W_ih[j * 96 + half * 48 + k];
    }
    __syncthreads();
    for (int k = 0; k < 48; ++k) {
      float4 w = *(const float4*)&WT[k * 196 + j0];
#pragma unroll
      for (int u = 0; u < 8; ++u) {
        float xv = xs[(tg * 8 + u) * 48 + half * 48 + k];
        acc[u][0] = fmaf(xv, w.x, acc[u][0]);
        acc[u][1] = fmaf(xv, w.y, acc[u][1]);
        acc[u][2] = fmaf(xv, w.z, acc[u][2]);
        acc[u][3] = fmaf(xv, w.w, acc[u][3]);
      }
    }
  }

#pragma unroll
  for (int u = 0; u < 8; ++u) {
    int tl = tg * 8 + u;
    if (tl < nt) {
      float4 st = make_float4(acc[u][0], acc[u][1], acc[u][2], acc[u][3]);
      *(float4*)&GI[(size_t)(b * NSn + t0 + tl) * G3n + j0] = st;
    }
  }
}

__global__ __attribute__((amdgpu_flat_work_group_size(64, 64),
                          amdgpu_waves_per_eu(1, 1),
                          amdgpu_num_vgpr(256)))
void gru_kernel(const float* __restrict__ GI,
                const float* __restrict__ W_hh,
                const float* __restrict__ b_hh,
                float* __restrict__ hs) {
  __shared__ __align__(16) float hbuf[64];
  gru_body<false>(GI, W_hh, b_hh, hs, hbuf, blockIdx.x, threadIdx.x, nullptr);
}

__global__ __launch_bounds__(256) void cs_kernel(const float* __restrict__ hs,
                                                 const float* __restrict__ W_cs,
                                                 const float* __restrict__ b_cs,
                                                 float* __restrict__ cs) {
  __shared__ __align__(16) float WcT[64 * 36];
  __shared__ __align__(16) float hsl[32 * 65];
  __shared__ __align__(16) float bcs[32];
  const int tile = blockIdx.x;
  const int b    = blockIdx.y;
  const int t0   = tile * 32;
  const int nt   = min(32, NSn - t0);
  const int tid  = threadIdx.x;

  for (int e = tid; e < 32 * 64; e += 256) {
    int i = e >> 6, k = e & 63;
    WcT[k * 36 + i] = W_cs[e];
  }
  for (int e = tid; e < nt * 64; e += 256) {
    int t = e >> 6, k = e & 63;
    hsl[t * 65 + k] = hs[((size_t)b * NSn + t0 + t) * GHn + k];
  }
  if (tid < 32) bcs[tid] = b_cs[tid];
  __syncthreads();

  const int oq = tid & 7;
  const int t  = tid >> 3;
  if (t < nt) {
    float4 acc = *(const float4*)&bcs[oq * 4];
    const float* hr = &hsl[t * 65];
#pragma unroll 4
    for (int k = 0; k < 64; ++k) {
      float hv = hr[k];
      float4 w = *(const float4*)&WcT[k * 36 + oq * 4];
      acc.x = fmaf(w.x, hv, acc.x);
      acc.y = fmaf(w.y, hv, acc.y);
      acc.z = fmaf(w.z, hv, acc.z);
      acc.w = fmaf(w.w, hv, acc.w);
    }
    *(float4*)&cs[((size_t)b * NSn + t0 + t) * 32 + oq * 4] = acc;
  }
}

__global__ __launch_bounds__(256) void out_kernel(const float* __restrict__ x,
                                                  const float* __restrict__ cs,
                                                  const float* __restrict__ W1,
                                                  const float* __restrict__ b1,
                                                  const float* __restrict__ W2,
                                                  const float* __restrict__ b2,
                                                  float* __restrict__ out) {
  __shared__ __align__(16) float A[33 * 65];
  __shared__ __align__(16) float W1T[64 * 68];
  __shared__ __align__(16) float W2T[64 * 36];
  __shared__ __align__(16) float h1loc[33 * 65];
  __shared__ __align__(16) float yloc[33 * 32];
  __shared__ __align__(16) float bb1[64];
  __shared__ __align__(16) float bb2[32];

  const int fb  = blockIdx.x;
  const int b   = blockIdx.y;
  const int f0  = fb * 32;
  const int nf  = min(33, NFn - f0);
  const int tid = threadIdx.x;

  for (int e = tid; e < 64 * 64; e += 256) {
    int o = e >> 6, k = e & 63;
    W1T[k * 68 + o] = W1[e];
  }
  for (int e = tid; e < 32 * 64; e += 256) {
    int o = e >> 6, k = e & 63;
    W2T[k * 36 + o] = W2[e];
  }
  if (tid < 64) bb1[tid] = b1[tid];
  if (tid < 32) bb2[tid] = b2[tid];

  for (int e = tid; e < 33 * 32; e += 256) {
    int lf = e >> 5, k = e & 31;
    int g = (f0 + lf) * 16 + k;
    A[lf * 65 + k] = (lf < nf && g < Tn) ? x[(size_t)b * Tn + g] : 0.0f;
  }
  for (int e = tid; e < 33 * 32; e += 256) {
    int lf = e >> 5, k = e & 31;
    int ts = max((f0 + lf) / 3 - 1, 0);
    A[lf * 65 + 32 + k] = (lf < nf) ? cs[((size_t)b * NSn + ts) * 32 + k] : 0.0f;
  }
  __syncthreads();

  for (int it = tid; it < 33 * 16; it += 256) {
    int lf = it >> 4, oq = it & 15;
    float4 acc = *(const float4*)&bb1[oq * 4];
    const float* ar = &A[lf * 65];
#pragma unroll 4
    for (int k = 0; k < 64; ++k) {
      float av = ar[k];
      float4 w = *(const float4*)&W1T[k * 68 + oq * 4];
      acc.x = fmaf(w.x, av, acc.x);
      acc.y = fmaf(w.y, av, acc.y);
      acc.z = fmaf(w.z, av, acc.z);
      acc.w = fmaf(w.w, av, acc.w);
    }
    acc.x = fmaxf(acc.x, 0.0f); acc.y = fmaxf(acc.y, 0.0f);
    acc.z = fmaxf(acc.z, 0.0f); acc.w = fmaxf(acc.w, 0.0f);
    *(float4*)&h1loc[lf * 65 + oq * 4] = acc;
  }
  __syncthreads();

  for (int it = tid; it < 33 * 8; it += 256) {
    int lf = it >> 3, oq = it & 7;
    float4 acc = *(const float4*)&bb2[oq * 4];
    const float* hr = &h1loc[lf * 65];
#pragma unroll 4
    for (int k = 0; k < 64; ++k) {
      float hv = hr[k];
      float4 w = *(const float4*)&W2T[k * 36 + oq * 4];
      acc.x = fmaf(w.x, hv, acc.x);
      acc.y = fmaf(w.y, hv, acc.y);
      acc.z = fmaf(w.z, hv, acc.z);
      acc.w = fmaf(w.w, hv, acc.w);
    }
    *(float4*)&yloc[lf * 32 + oq * 4] = acc;
  }
  __syncthreads();

  const int s0 = f0 * 16 + 16;
  const int s1 = min(s0 + 512, Tn);
  for (int s = s0 + tid; s < s1; s += 256) {
    int f1  = s >> 4;
    int o1  = s & 15;
    int lf1 = f1 - f0;
    float v = yloc[(lf1 - 1) * 32 + o1 + 16];
    if (lf1 < nf) v += yloc[lf1 * 32 + o1];
    out[(size_t)b * Tn + s] = v;
  }
  if (fb == 0 && tid < 16) out[(size_t)b * Tn + tid] = yloc[tid];
}

// ---------------------------------------------------------------------------
extern "C" void kernel_launch(void* const* d_in, const int* in_sizes, int n_in,
                              void* d_out, int out_size, void* d_ws, size_t ws_size,
                              hipStream_t stream) {
  const float* x    = (const float*)d_in[0];
  const float* W_ih = (const float*)d_in[1];
  const float* W_hh = (const float*)d_in[2];
  const float* b_ih = (const float*)d_in[3];
  const float* b_hh = (const float*)d_in[4];
  const float* W_cs = (const float*)d_in[5];
  const float* b_cs = (const float*)d_in[6];
  const float* W1   = (const float*)d_in[7];
  const float* b1   = (const float*)d_in[8];
  const float* W2   = (const float*)d_in[9];
  const float* b2   = (const float*)d_in[10];
  float* out = (float*)d_out;

  const size_t giN = (size_t)Bn * NSn * G3n;   // 98.2 MB
  const size_t hsN = (size_t)Bn * NSn * GHn;   // 32.7 MB
  const size_t uN  = (size_t)Bn * NFn * GHn;   // 98.3 MB

  float* GI = (float*)d_ws;
  float* hs = GI + giN;

  if (ws_size >= (giN + hsN + uN) * sizeof(float)) {
    // Fast path: r0-gi producers + polling gru + U, one grid.
    float* U = hs + hsN;
    float* d = GI;                             // GI dead after fat4
    // flags: first 16KB of `out` (r10 precedent; out2 overwrites all of out).
    unsigned int* flags = (unsigned int*)out;
    hipMemsetAsync(out, 0, (size_t)Bn * 32 * sizeof(unsigned int), stream);

    fat4_kernel<<<Bn + NGI + NU, 192, 0, stream>>>(
        x, W_ih, b_ih, W_hh, b_hh, W1, b1, GI, hs, U, flags);
    d_kernel<<<dim3(32, Bn), 256, 0, stream>>>(hs, W_cs, b_cs, W1, d);
    out2_kernel<<<dim3(94, Bn), 256, 0, stream>>>(U, d, W2, b2, out);
  } else {
    // Small-ws fallback: round-0 proven pipeline.
    float* cs = GI;
    gi_kernel<<<dim3(32, Bn), 192, 0, stream>>>(x, W_ih, b_ih, GI);
    gru_kernel<<<Bn, 64, 0, stream>>>(GI, W_hh, b_hh, hs);
    cs_kernel<<<dim3(32, Bn), 256, 0, stream>>>(hs, W_cs, b_cs, cs);
    out_kernel<<<dim3(94, Bn), 256, 0, stream>>>(x, cs, W1, b1, W2, b2, out);
  }
}

// Round 12
// 748.600 us; speedup vs baseline: 1.6655x; 1.5262x over previous
//
#include <hip/hip_runtime.h>

// Problem constants
constexpr int Bn  = 128;
constexpr int Tn  = 48000;
constexpr int NFn = 2999;   // fast frames
constexpr int NSn = 999;    // slow frames
constexpr int G3n = 192;    // 3*GH
constexpr int GHn = 64;

typedef float f2 __attribute__((ext_vector_type(2)));
typedef float f4 __attribute__((ext_vector_type(4)));

// ---------------------------------------------------------------------------
// Kernel 1: GI[b,t,j] = b_ih[j] + sum_{k<96} x[b,t*48+k] * W_ih[j,k]
// r11 change: W staged in QUARTERS of 24 k (WT 18.8KB vs 37.6KB) -> total
// LDS 25.2KB -> ~6 blocks/CU (was 3). gi has been ~150us across three
// instruction-level variants => occupancy/latency-bound, so double the
// resident waves. Per-accumulator k order stays 0..95 ascending =>
// bitwise-identical GI.
// ---------------------------------------------------------------------------
__global__ __launch_bounds__(192) void gi_kernel(const float* __restrict__ x,
                                                 const float* __restrict__ W_ih,
                                                 const float* __restrict__ b_ih,
                                                 float* __restrict__ GI) {
  __shared__ __align__(16) float WT[24 * 196];   // [k][j] quarter, stride 196
  __shared__ __align__(16) float xs[1584];       // 31*48+96 samples
  const int tile = blockIdx.x;        // 0..31
  const int b    = blockIdx.y;        // 0..127
  const int t0   = tile * 32;
  const int nt   = min(32, NSn - t0); // 32 or 7 (last tile)
  const int tid  = threadIdx.x;

  const int span = (nt - 1) * 48 + 96;
  for (int i = tid; i < 1584; i += 192)
    xs[i] = (i < span) ? x[(size_t)b * Tn + t0 * 48 + i] : 0.0f;

  const int jq = tid % 48;   // j-quad index
  const int tg = tid / 48;   // t-group (0..3)
  const int j0 = jq * 4;

  float acc[8][4];
#pragma unroll
  for (int u = 0; u < 8; ++u)
#pragma unroll
    for (int jj = 0; jj < 4; ++jj) acc[u][jj] = b_ih[j0 + jj];

  for (int qd = 0; qd < 4; ++qd) {
    __syncthreads();
    for (int e = tid; e < 192 * 24; e += 192) {
      int j = e / 24, k = e % 24;
      WT[k * 196 + j] = W_ih[j * 96 + qd * 24 + k];
    }
    __syncthreads();
    for (int kc = 0; kc < 24; kc += 4) {
      f4 wq[4];
#pragma unroll
      for (int kk = 0; kk < 4; ++kk)
        wq[kk] = *(const f4*)&WT[(kc + kk) * 196 + j0];
      f4 xq[8];
#pragma unroll
      for (int u = 0; u < 8; ++u)
        xq[u] = *(const f4*)&xs[(tg * 8 + u) * 48 + qd * 24 + kc];
      // k = qd*24 + kc + kk ascending per acc => overall 0..95 ascending:
      // bitwise-identical accumulation to the proven r0/r8 gi.
#pragma unroll
      for (int u = 0; u < 8; ++u) {
#pragma unroll
        for (int kk = 0; kk < 4; ++kk) {
          const float xv = xq[u][kk];
          acc[u][0] = fmaf(xv, wq[kk][0], acc[u][0]);
          acc[u][1] = fmaf(xv, wq[kk][1], acc[u][1]);
          acc[u][2] = fmaf(xv, wq[kk][2], acc[u][2]);
          acc[u][3] = fmaf(xv, wq[kk][3], acc[u][3]);
        }
      }
    }
  }

#pragma unroll
  for (int u = 0; u < 8; ++u) {
    int tl = tg * 8 + u;
    if (tl < nt) {
      float4 st = make_float4(acc[u][0], acc[u][1], acc[u][2], acc[u][3]);
      *(float4*)&GI[(size_t)(b * NSn + t0 + tl) * G3n + j0] = st;
    }
  }
}

// ---------------------------------------------------------------------------
// GRU body (round-0 proven, 485us).
// ---------------------------------------------------------------------------
__device__ __forceinline__ float fsigmoid(float v) {
  return __fdividef(1.0f, 1.0f + __expf(-v));
}
__device__ __forceinline__ float ftanh_f(float v) {
  return 1.0f - __fdividef(2.0f, __expf(2.0f * v) + 1.0f);
}

__device__ __forceinline__ void gru_body(const float* __restrict__ GI,
                                         const float* __restrict__ W_hh,
                                         const float* __restrict__ b_hh,
                                         float* __restrict__ hs,
                                         float* hbuf, int b, int j) {
  f2 wr2[32], wz2[32], wn2[32];
  const f2* Wr = (const f2*)(W_hh + (size_t)j * 64);
  const f2* Wz = (const f2*)(W_hh + (size_t)(j + 64) * 64);
  const f2* Wn = (const f2*)(W_hh + (size_t)(j + 128) * 64);
#pragma unroll
  for (int q = 0; q < 32; ++q) { wr2[q] = Wr[q]; wz2[q] = Wz[q]; wn2[q] = Wn[q]; }
  // Opaque to the compiler => cannot re-load from memory inside the loop.
#pragma unroll
  for (int q = 0; q < 32; ++q) {
    asm volatile("" : "+v"(wr2[q]));
    asm volatile("" : "+v"(wz2[q]));
    asm volatile("" : "+v"(wn2[q]));
  }
  const float br = b_hh[j], bz = b_hh[j + 64], bn = b_hh[j + 128];

  hbuf[j] = 0.0f;
  float hj = 0.0f;
  __builtin_amdgcn_wave_barrier();

  const float* gp = GI + (size_t)b * NSn * G3n;
  float* hsp = hs + (size_t)b * NSn * GHn;

  // distance-2 prefetch ring
  float pr0, pr1, pr2, pz0, pz1, pz2, pn0, pn1, pn2;
  pr0 = gp[0 * G3n + j];       pz0 = gp[0 * G3n + 64 + j];  pn0 = gp[0 * G3n + 128 + j];
  pr1 = gp[1 * G3n + j];       pz1 = gp[1 * G3n + 64 + j];  pn1 = gp[1 * G3n + 128 + j];

  for (int t = 0; t < NSn; ++t) {
    const size_t off = (size_t)min(t + 2, NSn - 1) * G3n;
    pr2 = gp[off + j];
    pz2 = gp[off + 64 + j];
    pn2 = gp[off + 128 + j];

    const f2* h2 = (const f2*)hbuf;
    f2 ar0 = {0.f, 0.f}, ar1 = {0.f, 0.f}, ar2 = {0.f, 0.f}, ar3 = {0.f, 0.f};
    f2 az0 = {0.f, 0.f}, az1 = {0.f, 0.f}, az2 = {0.f, 0.f}, az3 = {0.f, 0.f};
    f2 an0 = {0.f, 0.f}, an1 = {0.f, 0.f}, an2 = {0.f, 0.f}, an3 = {0.f, 0.f};
#pragma unroll
    for (int q = 0; q < 8; ++q) {
      f2 h0 = h2[q * 4 + 0], h1 = h2[q * 4 + 1], h2v = h2[q * 4 + 2], h3 = h2[q * 4 + 3];
      ar0 += wr2[q * 4 + 0] * h0; ar1 += wr2[q * 4 + 1] * h1;
      ar2 += wr2[q * 4 + 2] * h2v; ar3 += wr2[q * 4 + 3] * h3;
      az0 += wz2[q * 4 + 0] * h0; az1 += wz2[q * 4 + 1] * h1;
      az2 += wz2[q * 4 + 2] * h2v; az3 += wz2[q * 4 + 3] * h3;
      an0 += wn2[q * 4 + 0] * h0; an1 += wn2[q * 4 + 1] * h1;
      an2 += wn2[q * 4 + 2] * h2v; an3 += wn2[q * 4 + 3] * h3;
    }
    f2 sr = (ar0 + ar1) + (ar2 + ar3);
    f2 sz = (az0 + az1) + (az2 + az3);
    f2 sn = (an0 + an1) + (an2 + an3);

    float r = fsigmoid(pr0 + br + sr.x + sr.y);
    float z = fsigmoid(pz0 + bz + sz.x + sz.y);
    float n = ftanh_f(fmaf(r, bn + sn.x + sn.y, pn0));
    float hn = fmaf(z, hj - n, n);          // (1-z)*n + z*h

    __builtin_amdgcn_wave_barrier();
    hbuf[j] = hn;
    __builtin_amdgcn_wave_barrier();
    hj = hn;
    hsp[(size_t)t * GHn + j] = hn;

    pr0 = pr1; pr1 = pr2;
    pz0 = pz1; pz1 = pz2;
    pn0 = pn1; pn1 = pn2;
  }
}

// Standalone gru (small-ws fallback path).
__global__ __attribute__((amdgpu_flat_work_group_size(64, 64),
                          amdgpu_waves_per_eu(1, 1),
                          amdgpu_num_vgpr(256)))
void gru_kernel(const float* __restrict__ GI,
                const float* __restrict__ W_hh,
                const float* __restrict__ b_hh,
                float* __restrict__ hs) {
  __shared__ __align__(16) float hbuf[64];
  gru_body(GI, W_hh, b_hh, hs, hbuf, blockIdx.x, threadIdx.x);
}

// ---------------------------------------------------------------------------
// FAT kernel (r8 proven, 494us): blocks [0,128) gru at setprio(1); rest U.
// ---------------------------------------------------------------------------
constexpr int UCHUNK = 125;
constexpr int NCH    = 24;            // 24*125 = 3000 >= 2999

__global__ __attribute__((amdgpu_flat_work_group_size(64, 64),
                          amdgpu_waves_per_eu(1, 1),
                          amdgpu_num_vgpr(256)))
void fat_kernel(const float* __restrict__ GI,
                const float* __restrict__ W_hh,
                const float* __restrict__ b_hh,
                float* __restrict__ hs,
                const float* __restrict__ x,
                const float* __restrict__ W1,
                const float* __restrict__ b1,
                float* __restrict__ U) {
  __shared__ __align__(16) float hbuf[64];
  __shared__ __align__(16) float xs[UCHUNK * 16 + 16];   // 2016
  const int tid = threadIdx.x;

  if (blockIdx.x < Bn) {
    __builtin_amdgcn_s_setprio(1);     // favor the serial GRU pole
    gru_body(GI, W_hh, b_hh, hs, hbuf, blockIdx.x, tid);
    __builtin_amdgcn_s_setprio(0);
    return;
  }

  const int ub = blockIdx.x - Bn;
  const int b  = ub / NCH;
  const int ch = ub % NCH;
  const int fA = ch * UCHUNK;
  const int fE = min(fA + UCHUNK, NFn);
  const int o  = tid;

  const int nsamp = (fE - fA - 1) * 16 + 32;
  for (int i = tid; i < nsamp; i += 64)
    xs[i] = x[(size_t)b * Tn + fA * 16 + i];

  f4 w1f[8];
#pragma unroll
  for (int i = 0; i < 8; ++i)
    w1f[i] = *(const f4*)&W1[(size_t)o * 64 + 4 * i];
  const float bo = b1[o];
  __syncthreads();

  float* Up = U + ((size_t)b * NFn) * GHn + o;
  for (int f = fA; f < fE; ++f) {
    const f4* xq = (const f4*)&xs[(f - fA) * 16];
    float a0 = bo, a1 = 0.f, a2 = 0.f, a3 = 0.f;
#pragma unroll
    for (int i = 0; i < 8; ++i) {
      f4 xv = xq[i];
      a0 = fmaf(xv[0], w1f[i][0], a0);
      a1 = fmaf(xv[1], w1f[i][1], a1);
      a2 = fmaf(xv[2], w1f[i][2], a2);
      a3 = fmaf(xv[3], w1f[i][3], a3);
    }
    Up[(size_t)f * GHn] = (a0 + a1) + (a2 + a3);
  }
}

// ---------------------------------------------------------------------------
// d_kernel: d[b,ts,o] = (c_s @ W1_cond^T), c_s = hs @ W_cs^T + b_cs  (proven)
// ---------------------------------------------------------------------------
__global__ __launch_bounds__(256) void d_kernel(const float* __restrict__ hs,
                                                const float* __restrict__ W_cs,
                                                const float* __restrict__ b_cs,
                                                const float* __restrict__ W1,
                                                float* __restrict__ d) {
  __shared__ __align__(16) float WcT[64 * 36];   // [k][i] stride 36
  __shared__ __align__(16) float W1cT[32 * 68];  // [i][o] stride 68
  __shared__ __align__(16) float hsl[32 * 65];   // [t][k] stride 65
  __shared__ __align__(16) float cloc[32 * 36];  // [t][i] stride 36
  __shared__ __align__(16) float bcs[32];
  const int tile = blockIdx.x;   // 0..31
  const int b    = blockIdx.y;
  const int t0   = tile * 32;
  const int nt   = min(32, NSn - t0);
  const int tid  = threadIdx.x;

  for (int e = tid; e < 32 * 64; e += 256) {
    int i = e >> 6, k = e & 63;
    WcT[k * 36 + i] = W_cs[e];
  }
  for (int e = tid; e < 64 * 32; e += 256) {
    int o = e >> 5, i = e & 31;
    W1cT[i * 68 + o] = W1[(size_t)o * 64 + 32 + i];
  }
  for (int e = tid; e < nt * 64; e += 256) {
    int t = e >> 6, k = e & 63;
    hsl[t * 65 + k] = hs[((size_t)b * NSn + t0 + t) * GHn + k];
  }
  if (tid < 32) bcs[tid] = b_cs[tid];
  __syncthreads();

  {
    const int iq = tid & 7;
    const int t  = tid >> 3;
    if (t < nt) {
      float4 acc = *(const float4*)&bcs[iq * 4];
      const float* hr = &hsl[t * 65];
#pragma unroll 4
      for (int k = 0; k < 64; ++k) {
        float hv = hr[k];
        float4 w = *(const float4*)&WcT[k * 36 + iq * 4];
        acc.x = fmaf(w.x, hv, acc.x);
        acc.y = fmaf(w.y, hv, acc.y);
        acc.z = fmaf(w.z, hv, acc.z);
        acc.w = fmaf(w.w, hv, acc.w);
      }
      *(float4*)&cloc[t * 36 + iq * 4] = acc;
    }
  }
  __syncthreads();

  for (int it = tid; it < 32 * 16; it += 256) {
    const int oq = it & 15;
    const int t  = it >> 4;
    if (t < nt) {
      float a0 = 0.f, a1 = 0.f, a2 = 0.f, a3 = 0.f;
      const float* cr = &cloc[t * 36];
#pragma unroll 4
      for (int i = 0; i < 32; ++i) {
        float cv = cr[i];
        float4 w = *(const float4*)&W1cT[i * 68 + oq * 4];
        a0 = fmaf(w.x, cv, a0);
        a1 = fmaf(w.y, cv, a1);
        a2 = fmaf(w.z, cv, a2);
        a3 = fmaf(w.w, cv, a3);
      }
      float4 st = make_float4(a0, a1, a2, a3);
      *(float4*)&d[((size_t)b * NSn + t0 + t) * GHn + oq * 4] = st;
    }
  }
}

// ---------------------------------------------------------------------------
// cs_kernel (small-ws fallback only)
// ---------------------------------------------------------------------------
__global__ __launch_bounds__(256) void cs_kernel(const float* __restrict__ hs,
                                                 const float* __restrict__ W_cs,
                                                 const float* __restrict__ b_cs,
                                                 float* __restrict__ cs) {
  __shared__ __align__(16) float WcT[64 * 36];
  __shared__ __align__(16) float hsl[32 * 65];
  __shared__ __align__(16) float bcs[32];
  const int tile = blockIdx.x;
  const int b    = blockIdx.y;
  const int t0   = tile * 32;
  const int nt   = min(32, NSn - t0);
  const int tid  = threadIdx.x;

  for (int e = tid; e < 32 * 64; e += 256) {
    int i = e >> 6, k = e & 63;
    WcT[k * 36 + i] = W_cs[e];
  }
  for (int e = tid; e < nt * 64; e += 256) {
    int t = e >> 6, k = e & 63;
    hsl[t * 65 + k] = hs[((size_t)b * NSn + t0 + t) * GHn + k];
  }
  if (tid < 32) bcs[tid] = b_cs[tid];
  __syncthreads();

  const int oq = tid & 7;
  const int t  = tid >> 3;
  if (t < nt) {
    float4 acc = *(const float4*)&bcs[oq * 4];
    const float* hr = &hsl[t * 65];
#pragma unroll 4
    for (int k = 0; k < 64; ++k) {
      float hv = hr[k];
      float4 w = *(const float4*)&WcT[k * 36 + oq * 4];
      acc.x = fmaf(w.x, hv, acc.x);
      acc.y = fmaf(w.y, hv, acc.y);
      acc.z = fmaf(w.z, hv, acc.z);
      acc.w = fmaf(w.w, hv, acc.w);
    }
    *(float4*)&cs[((size_t)b * NSn + t0 + t) * 32 + oq * 4] = acc;
  }
}

// ---------------------------------------------------------------------------
// out2: h = relu(U + d[ts]), y = h@W2^T + b2, overlap-add  (proven)
// ---------------------------------------------------------------------------
__global__ __launch_bounds__(256) void out2_kernel(const float* __restrict__ U,
                                                   const float* __restrict__ d,
                                                   const float* __restrict__ W2,
                                                   const float* __restrict__ b2,
                                                   float* __restrict__ out) {
  __shared__ __align__(16) float h1loc[33 * 68];
  __shared__ __align__(16) float W2T[64 * 36];
  __shared__ __align__(16) float yloc[33 * 32];
  __shared__ __align__(16) float dloc[12][68];
  __shared__ __align__(16) float bb2[32];

  const int fb  = blockIdx.x;
  const int b   = blockIdx.y;
  const int f0  = fb * 32;
  const int nf  = min(33, NFn - f0);
  const int tid = threadIdx.x;
  const int ts0 = max(f0 / 3 - 1, 0);

  for (int e = tid; e < 32 * 64; e += 256) {
    int o = e >> 6, k = e & 63;
    W2T[k * 36 + o] = W2[e];
  }
  if (tid < 32) bb2[tid] = b2[tid];
  for (int e = tid; e < 12 * 64; e += 256) {
    int ti = e >> 6, o = e & 63;
    int ts = min(ts0 + ti, NSn - 1);
    dloc[ti][o] = d[((size_t)b * NSn + ts) * GHn + o];
  }
  __syncthreads();

  for (int it = tid; it < 33 * 16; it += 256) {
    const int lf = it >> 4, oq = it & 15;
    const int f  = f0 + lf;
    f4 s = {0.f, 0.f, 0.f, 0.f};
    if (f < NFn) {
      f4 u  = *(const f4*)&U[((size_t)b * NFn + f) * GHn + oq * 4];
      const int ti = max(f / 3 - 1, 0) - ts0;
      f4 dv = *(const f4*)&dloc[ti][oq * 4];
      s = u + dv;
#pragma unroll
      for (int c = 0; c < 4; ++c) s[c] = fmaxf(s[c], 0.f);
    }
    *(f4*)&h1loc[lf * 68 + oq * 4] = s;
  }
  __syncthreads();

  for (int it = tid; it < 33 * 8; it += 256) {
    const int lf = it >> 3, oq = it & 7;
    float4 acc = *(const float4*)&bb2[oq * 4];
    const float* hr = &h1loc[lf * 68];
#pragma unroll 4
    for (int k = 0; k < 64; ++k) {
      float hv = hr[k];
      float4 w = *(const float4*)&W2T[k * 36 + oq * 4];
      acc.x = fmaf(w.x, hv, acc.x);
      acc.y = fmaf(w.y, hv, acc.y);
      acc.z = fmaf(w.z, hv, acc.z);
      acc.w = fmaf(w.w, hv, acc.w);
    }
    *(float4*)&yloc[lf * 32 + oq * 4] = acc;
  }
  __syncthreads();

  const int s0 = f0 * 16 + 16;
  const int s1 = min(s0 + 512, Tn);
  for (int s = s0 + tid; s < s1; s += 256) {
    int f1  = s >> 4;
    int o1  = s & 15;
    int lf1 = f1 - f0;
    float v = yloc[(lf1 - 1) * 32 + o1 + 16];
    if (lf1 < nf) v += yloc[lf1 * 32 + o1];
    out[(size_t)b * Tn + s] = v;
  }
  if (fb == 0 && tid < 16) out[(size_t)b * Tn + tid] = yloc[tid];
}

// ---------------------------------------------------------------------------
// out_kernel (small-ws fallback only): round-0 fused MLP + OA
// ---------------------------------------------------------------------------
__global__ __launch_bounds__(256) void out_kernel(const float* __restrict__ x,
                                                  const float* __restrict__ cs,
                                                  const float* __restrict__ W1,
                                                  const float* __restrict__ b1,
                                                  const float* __restrict__ W2,
                                                  const float* __restrict__ b2,
                                                  float* __restrict__ out) {
  __shared__ __align__(16) float A[33 * 65];
  __shared__ __align__(16) float W1T[64 * 68];
  __shared__ __align__(16) float W2T[64 * 36];
  __shared__ __align__(16) float h1loc[33 * 65];
  __shared__ __align__(16) float yloc[33 * 32];
  __shared__ __align__(16) float bb1[64];
  __shared__ __align__(16) float bb2[32];

  const int fb  = blockIdx.x;
  const int b   = blockIdx.y;
  const int f0  = fb * 32;
  const int nf  = min(33, NFn - f0);
  const int tid = threadIdx.x;

  for (int e = tid; e < 64 * 64; e += 256) {
    int o = e >> 6, k = e & 63;
    W1T[k * 68 + o] = W1[e];
  }
  for (int e = tid; e < 32 * 64; e += 256) {
    int o = e >> 6, k = e & 63;
    W2T[k * 36 + o] = W2[e];
  }
  if (tid < 64) bb1[tid] = b1[tid];
  if (tid < 32) bb2[tid] = b2[tid];

  for (int e = tid; e < 33 * 32; e += 256) {
    int lf = e >> 5, k = e & 31;
    int g = (f0 + lf) * 16 + k;
    A[lf * 65 + k] = (lf < nf && g < Tn) ? x[(size_t)b * Tn + g] : 0.0f;
  }
  for (int e = tid; e < 33 * 32; e += 256) {
    int lf = e >> 5, k = e & 31;
    int ts = max((f0 + lf) / 3 - 1, 0);
    A[lf * 65 + 32 + k] = (lf < nf) ? cs[((size_t)b * NSn + ts) * 32 + k] : 0.0f;
  }
  __syncthreads();

  for (int it = tid; it < 33 * 16; it += 256) {
    int lf = it >> 4, oq = it & 15;
    float4 acc = *(const float4*)&bb1[oq * 4];
    const float* ar = &A[lf * 65];
#pragma unroll 4
    for (int k = 0; k < 64; ++k) {
      float av = ar[k];
      float4 w = *(const float4*)&W1T[k * 68 + oq * 4];
      acc.x = fmaf(w.x, av, acc.x);
      acc.y = fmaf(w.y, av, acc.y);
      acc.z = fmaf(w.z, av, acc.z);
      acc.w = fmaf(w.w, av, acc.w);
    }
    acc.x = fmaxf(acc.x, 0.0f); acc.y = fmaxf(acc.y, 0.0f);
    acc.z = fmaxf(acc.z, 0.0f); acc.w = fmaxf(acc.w, 0.0f);
    *(float4*)&h1loc[lf * 65 + oq * 4] = acc;
  }
  __syncthreads();

  for (int it = tid; it < 33 * 8; it += 256) {
    int lf = it >> 3, oq = it & 7;
    float4 acc = *(const float4*)&bb2[oq * 4];
    const float* hr = &h1loc[lf * 65];
#pragma unroll 4
    for (int k = 0; k < 64; ++k) {
      float hv = hr[k];
      float4 w = *(const float4*)&W2T[k * 36 + oq * 4];
      acc.x = fmaf(w.x, hv, acc.x);
      acc.y = fmaf(w.y, hv, acc.y);
      acc.z = fmaf(w.z, hv, acc.z);
      acc.w = fmaf(w.w, hv, acc.w);
    }
    *(float4*)&yloc[lf * 32 + oq * 4] = acc;
  }
  __syncthreads();

  const int s0 = f0 * 16 + 16;
  const int s1 = min(s0 + 512, Tn);
  for (int s = s0 + tid; s < s1; s += 256) {
    int f1  = s >> 4;
    int o1  = s & 15;
    int lf1 = f1 - f0;
    float v = yloc[(lf1 - 1) * 32 + o1 + 16];
    if (lf1 < nf) v += yloc[lf1 * 32 + o1];
    out[(size_t)b * Tn + s] = v;
  }
  if (fb == 0 && tid < 16) out[(size_t)b * Tn + tid] = yloc[tid];
}

// ---------------------------------------------------------------------------
extern "C" void kernel_launch(void* const* d_in, const int* in_sizes, int n_in,
                              void* d_out, int out_size, void* d_ws, size_t ws_size,
                              hipStream_t stream) {
  const float* x    = (const float*)d_in[0];
  const float* W_ih = (const float*)d_in[1];
  const float* W_hh = (const float*)d_in[2];
  const float* b_ih = (const float*)d_in[3];
  const float* b_hh = (const float*)d_in[4];
  const float* W_cs = (const float*)d_in[5];
  const float* b_cs = (const float*)d_in[6];
  const float* W1   = (const float*)d_in[7];
  const float* b1   = (const float*)d_in[8];
  const float* W2   = (const float*)d_in[9];
  const float* b2   = (const float*)d_in[10];
  float* out = (float*)d_out;

  const size_t giN = (size_t)Bn * NSn * G3n;   // 98.2 MB
  const size_t hsN = (size_t)Bn * NSn * GHn;   // 32.7 MB
  const size_t uN  = (size_t)Bn * NFn * GHn;   // 98.3 MB

  float* GI = (float*)d_ws;
  float* hs = GI + giN;

  gi_kernel<<<dim3(32, Bn), 192, 0, stream>>>(x, W_ih, b_ih, GI);

  if (ws_size >= (giN + hsN + uN) * sizeof(float)) {
    // r8 proven fast path: gru overlapped with U precompute.
    float* U = hs + hsN;
    float* d = GI;                             // GI dead after fat
    fat_kernel<<<Bn + Bn * NCH, 64, 0, stream>>>(GI, W_hh, b_hh, hs,
                                                 x, W1, b1, U);
    d_kernel<<<dim3(32, Bn), 256, 0, stream>>>(hs, W_cs, b_cs, W1, d);
    out2_kernel<<<dim3(94, Bn), 256, 0, stream>>>(U, d, W2, b2, out);
  } else {
    // Small-ws fallback: round-0 pipeline.
    float* cs = GI;
    gru_kernel<<<Bn, 64, 0, stream>>>(GI, W_hh, b_hh, hs);
    cs_kernel<<<dim3(32, Bn), 256, 0, stream>>>(hs, W_cs, b_cs, cs);
    out_kernel<<<dim3(94, Bn), 256, 0, stream>>>(x, cs, W1, b1, W2, b2, out);
  }
}